// Round 15
// baseline (34.966 us; speedup 1.0000x reference)
//
#include <hip/hip_runtime.h>
#include <math.h>

#define NB 4
#define NN 4096
#define QSCALE 0.1803368801f   // (1/sqrt(64)) * log2(e): scores in log2 domain

#define KS 16                  // key splits per q-tile
#define KPB 256                // keys per block chunk
#define STK 64                 // keys per supertile (8 KB staged)
#define NST (KPB / STK)        // 4 supertiles
#define NG 2                   // q-groups per wave (32 queries); q-tile = 128
#define NQT (NB * 32)          // q-tiles (128 queries each) = 128

typedef __bf16 bf16x8 __attribute__((ext_vector_type(8)));
typedef float f32x4 __attribute__((ext_vector_type(4)));
typedef float f32x2 __attribute__((ext_vector_type(2)));

union BF8 { unsigned short u[8]; bf16x8 v; uint4 q; };

static __device__ inline unsigned short f2bf(float f) {
    union { float f; unsigned u; } v; v.f = f;
    unsigned r = v.u + 0x7fffu + ((v.u >> 16) & 1u);   // RNE
    return (unsigned short)(r >> 16);
}

// ---------------------------------------------------------------------------
// Kernel 1 (MFMA prep, 16 positions/block, 1024 blocks = 4/CU, 16 waves/CU):
// wave roles: wid<2 -> Q (d-half wid&1), wid>=2 -> K (d-half wid&1).
// Per wave: 2 c-tiles x 2 MFMA (half the serial chain of the old 512-block
// version). wve = Wo·Wv, cv = Wo·bv wave-parallel; VW = wve·x + cv.
// ---------------------------------------------------------------------------
__global__ __launch_bounds__(256) void prep_mfma(
    const float* __restrict__ x,
    const float* __restrict__ Wq, const float* __restrict__ bq,
    const float* __restrict__ Wk, const float* __restrict__ bk,
    const float* __restrict__ Wv, const float* __restrict__ bv,
    const float* __restrict__ Wo,
    unsigned short* __restrict__ Qb, unsigned short* __restrict__ Kb,
    float* __restrict__ VW)
{
    __shared__ float xt[64 * 20];                 // [c][n16], pad 20 (16B-aligned rows)
    __shared__ float wve_s[64];
    __shared__ unsigned short rows[4][16 * 40];   // per-wave 16 pos x 32 d (+pad)

    const int blk = blockIdx.x;                   // NB*256
    const int b = blk >> 8;
    const int n0 = (blk & 255) << 4;
    const int tid = threadIdx.x;
    const int wid = tid >> 6, lane = tid & 63;
    const int lg = lane >> 4, ll = lane & 15;

    // x-tile: one float4 per thread (64 rows x 16 cols)
    {
        int c = tid >> 2, nq = tid & 3;
        float4 v = *(const float4*)(x + (size_t)b * 64 * NN + (size_t)c * NN + n0 + nq * 4);
        *(float4*)&xt[c * 20 + nq * 4] = v;
    }
    // wve[c] = sum_e Wo[e]*Wv[e*64+c], 4 lanes per c
    {
        int c = tid >> 2, part = tid & 3;
        float a = 0.f;
        #pragma unroll
        for (int j = 0; j < 16; ++j) {
            int e = part * 16 + j;
            a = fmaf(Wo[e], Wv[e * 64 + c], a);
        }
        a += __shfl_xor(a, 1);
        a += __shfl_xor(a, 2);
        if (part == 0) wve_s[c] = a;
    }
    // cv = Wo·bv via full-wave butterfly
    float cv;
    {
        float p = Wo[lane] * bv[lane];
        #pragma unroll
        for (int off = 1; off < 64; off <<= 1) p += __shfl_xor(p, off);
        cv = p;
    }
    __syncthreads();

    // VW: 16 lanes per position, 4 c's each
    {
        int pos = tid >> 4, part = tid & 15;
        float a = 0.f;
        #pragma unroll
        for (int j = 0; j < 4; ++j) {
            int c = part * 4 + j;
            a = fmaf(wve_s[c], xt[c * 20 + pos], a);
        }
        a += __shfl_xor(a, 1);
        a += __shfl_xor(a, 2);
        a += __shfl_xor(a, 4);
        a += __shfl_xor(a, 8);
        if (part == 0) VW[(size_t)b * NN + n0 + pos] = a + cv;
    }

    // A fragments: 16 positions (rows = ll), k = c
    BF8 a0, a1;
    #pragma unroll
    for (int j = 0; j < 8; ++j) {
        a0.v[j] = (__bf16)xt[(lg * 8 + j) * 20 + ll];
        a1.v[j] = (__bf16)xt[(32 + lg * 8 + j) * 20 + ll];
    }

    const int proj = wid >> 1;                    // 0: Q, 1: K
    const int ctbase = (wid & 1) * 2;             // d-range ctbase*16 .. +32
    const float* W  = proj ? Wk : Wq;
    const float* bs = proj ? bk : bq;
    unsigned short* Out = proj ? Kb : Qb;
    const float scale = proj ? 1.f : QSCALE;
    unsigned short* myrows = rows[wid];

    #pragma unroll
    for (int cc = 0; cc < 2; ++cc) {
        int ct = ctbase + cc;
        const float* wr = W + (ct * 16 + ll) * 64;
        float4 f0 = *(const float4*)(wr + lg * 8);
        float4 f1 = *(const float4*)(wr + lg * 8 + 4);
        float4 f2 = *(const float4*)(wr + 32 + lg * 8);
        float4 f3 = *(const float4*)(wr + 32 + lg * 8 + 4);
        BF8 w0, w1;
        w0.v[0] = (__bf16)f0.x; w0.v[1] = (__bf16)f0.y; w0.v[2] = (__bf16)f0.z; w0.v[3] = (__bf16)f0.w;
        w0.v[4] = (__bf16)f1.x; w0.v[5] = (__bf16)f1.y; w0.v[6] = (__bf16)f1.z; w0.v[7] = (__bf16)f1.w;
        w1.v[0] = (__bf16)f2.x; w1.v[1] = (__bf16)f2.y; w1.v[2] = (__bf16)f2.z; w1.v[3] = (__bf16)f2.w;
        w1.v[4] = (__bf16)f3.x; w1.v[5] = (__bf16)f3.y; w1.v[6] = (__bf16)f3.z; w1.v[7] = (__bf16)f3.w;
        f32x4 acc = {0.f, 0.f, 0.f, 0.f};
        acc = __builtin_amdgcn_mfma_f32_16x16x32_bf16(a0.v, w0.v, acc, 0, 0, 0);
        acc = __builtin_amdgcn_mfma_f32_16x16x32_bf16(a1.v, w1.v, acc, 0, 0, 0);
        float bias = bs[ct * 16 + ll];
        #pragma unroll
        for (int r = 0; r < 4; ++r)
            myrows[(lg * 4 + r) * 40 + cc * 16 + ll] = f2bf((acc[r] + bias) * scale);
    }
    // wave-local transpose readback: 4 lanes per position, 16B each
    {
        int pos = lane >> 2, seg = lane & 3;
        uint4 v = *(const uint4*)&myrows[pos * 40 + seg * 8];
        *(uint4*)(Out + ((size_t)b * NN + n0 + pos) * 64 + ctbase * 16 + seg * 8) = v;
    }
}

// ---------------------------------------------------------------------------
// Kernel 2: MFMA attention — unchanged from R14 (KS=16, NG=2, LDS dbuf,
// packed (Z,A) accumulate, 16B XOR swizzle write+read).
// ---------------------------------------------------------------------------
__global__ __launch_bounds__(256) void attn_mfma(
    const unsigned short* __restrict__ Qb, const unsigned short* __restrict__ Kb,
    const float* __restrict__ VW, float2* __restrict__ P2)
{
    __shared__ unsigned short kbuf[2][STK * 64];   // 2 x 8 KB, swizzled
    __shared__ float vws[KPB];                     // 1 KB
    const int blk = blockIdx.x;                // ((b*32 + qt)*KS + ks)
    const int ks = blk & (KS - 1);
    const int t = blk >> 4;                    // 0..127
    const int b = t >> 5;
    const int q0 = (t & 31) << 7;              // 128-query tile
    const int tid = threadIdx.x;
    const int wid = tid >> 6, lane = tid & 63;
    const int lg = lane >> 4, ll = lane & 15;

    vws[tid] = VW[(size_t)b * NN + ks * KPB + tid];

    bf16x8 qfa[NG], qfb[NG];
    #pragma unroll
    for (int g = 0; g < NG; ++g) {
        const unsigned short* qp =
            Qb + ((size_t)b * NN + q0 + g * 64 + wid * 16 + ll) * 64 + lg * 8;
        qfa[g] = *(const bf16x8*)qp;
        qfb[g] = *(const bf16x8*)(qp + 32);
    }

    const char* kchunk = (const char*)(Kb + ((size_t)b * NN + ks * KPB) * 64);
    const int d0 = tid * 16, d1 = 4096 + tid * 16;
    const int sw0 = d0 ^ (((d0 >> 7) & 7) << 4);
    const int sw1 = d1 ^ (((d1 >> 7) & 7) << 4);
    const int c0 = (lg ^ (ll & 7)) & 7;
    const int c1 = ((lg + 4) ^ (ll & 7)) & 7;

    {   // prologue: stage supertile 0 into buf 0
        uint4 r0 = *(const uint4*)(kchunk + d0);
        uint4 r1 = *(const uint4*)(kchunk + d1);
        *(uint4*)((char*)kbuf[0] + sw0) = r0;
        *(uint4*)((char*)kbuf[0] + sw1) = r1;
    }
    __syncthreads();

    f32x2 ZA[NG];
    #pragma unroll
    for (int g = 0; g < NG; ++g) ZA[g] = (f32x2){0.f, 0.f};

    int cur = 0;
    #pragma unroll 1
    for (int st = 0; st < NST; ++st) {
        uint4 r0, r1;
        const bool more = (st + 1 < NST);
        if (more) {
            const char* src = kchunk + (size_t)(st + 1) * 8192;
            r0 = *(const uint4*)(src + d0);
            r1 = *(const uint4*)(src + d1);
        }
        const char* kb = (const char*)kbuf[cur];
        #pragma unroll
        for (int kt = 0; kt < 4; ++kt) {
            const int rowb = (kt * 16 + ll) * 128;
            const bf16x8 k0 = *(const bf16x8*)(kb + rowb + (c0 << 4));
            const bf16x8 k1 = *(const bf16x8*)(kb + rowb + (c1 << 4));
            const float4 vv = *(const float4*)&vws[st * 64 + kt * 16 + lg * 4];
            const f32x2 w0 = {1.f, vv.x}, w1 = {1.f, vv.y};
            const f32x2 w2 = {1.f, vv.z}, w3 = {1.f, vv.w};
            #pragma unroll
            for (int g = 0; g < NG; ++g) {
                f32x4 acc = {0.f, 0.f, 0.f, 0.f};
                acc = __builtin_amdgcn_mfma_f32_16x16x32_bf16(k0, qfa[g], acc, 0, 0, 0);
                acc = __builtin_amdgcn_mfma_f32_16x16x32_bf16(k1, qfb[g], acc, 0, 0, 0);
                float e0 = __builtin_amdgcn_exp2f(acc[0]);
                float e1 = __builtin_amdgcn_exp2f(acc[1]);
                float e2 = __builtin_amdgcn_exp2f(acc[2]);
                float e3 = __builtin_amdgcn_exp2f(acc[3]);
                ZA[g] = __builtin_elementwise_fma((f32x2){e0, e0}, w0, ZA[g]);
                ZA[g] = __builtin_elementwise_fma((f32x2){e1, e1}, w1, ZA[g]);
                ZA[g] = __builtin_elementwise_fma((f32x2){e2, e2}, w2, ZA[g]);
                ZA[g] = __builtin_elementwise_fma((f32x2){e3, e3}, w3, ZA[g]);
            }
        }
        if (more) {
            char* dst = (char*)kbuf[cur ^ 1];
            *(uint4*)(dst + sw0) = r0;
            *(uint4*)(dst + sw1) = r1;
            __syncthreads();
            cur ^= 1;
        }
    }

    #pragma unroll
    for (int g = 0; g < NG; ++g) {
        float Z = ZA[g].x, A = ZA[g].y;
        Z += __shfl_xor(Z, 16); Z += __shfl_xor(Z, 32);
        A += __shfl_xor(A, 16); A += __shfl_xor(A, 32);
        if (lg == 0)
            P2[((size_t)ks << 14) + ((size_t)b << 12) + q0 + g * 64 + wid * 16 + ll] =
                make_float2(Z, A);
    }
}

// ---------------------------------------------------------------------------
// Kernel 3: sum KS additive partials, sigmoid(A/Z + bo). 256 blocks x 64.
// ---------------------------------------------------------------------------
__global__ __launch_bounds__(64) void combine_kernel(
    const float2* __restrict__ P2, const float* __restrict__ bo,
    float* __restrict__ out)
{
    int i = blockIdx.x * 64 + threadIdx.x;     // NB*NN = 16384
    float Z = 0.f, A = 0.f;
    #pragma unroll
    for (int r = 0; r < KS; ++r) {
        float2 p = P2[((size_t)r << 14) + i];
        Z += p.x; A += p.y;
    }
    float y = A / Z + bo[0];
    out[i] = 1.f / (1.f + __expf(-y));
}

extern "C" void kernel_launch(void* const* d_in, const int* in_sizes, int n_in,
                              void* d_out, int out_size, void* d_ws, size_t ws_size,
                              hipStream_t stream)
{
    const float* x  = (const float*)d_in[0];
    const float* Wq = (const float*)d_in[1];
    const float* bq = (const float*)d_in[2];
    const float* Wk = (const float*)d_in[3];
    const float* bk = (const float*)d_in[4];
    const float* Wv = (const float*)d_in[5];
    const float* bv = (const float*)d_in[6];
    const float* Wo = (const float*)d_in[7];
    const float* bo = (const float*)d_in[8];
    float* out = (float*)d_out;

    unsigned short* Qb = (unsigned short*)d_ws;            // 2 MB
    unsigned short* Kb = Qb + (size_t)NB * NN * 64;        // 2 MB
    float* VW = (float*)(Kb + (size_t)NB * NN * 64);       // 64 KB
    float2* P2 = (float2*)(VW + (size_t)NB * NN);          // 2 MB

    prep_mfma<<<NB * 256, 256, 0, stream>>>(x, Wq, bq, Wk, bk, Wv, bv, Wo,
                                            Qb, Kb, VW);
    attn_mfma<<<NQT * KS, 256, 0, stream>>>(Qb, Kb, VW, P2);
    combine_kernel<<<(NB * NN) / 64, 64, 0, stream>>>(P2, bo, out);
}